// Round 4
// baseline (23.305 us; speedup 1.0000x reference)
//
#include <hip/hip_runtime.h>

// RegionAttention: bin 8M landmarks into a 512x512 grid; out[i] = enhanced[i]
// if any landmark falls in bin i else 1.0f.
//
// Round 4: pass 1 at 100% occupancy (512 blocks x 1024 thr = 2 blocks/CU,
// 2 x 32KB LDS masks per CU = 64KB of 160KB). Round-3 ran 1 block/CU
// (16 waves = 50%) and sat ~6us above the 64MB-stream floor -> latency
// hiding hypothesis. Per-CU VALU/ds_or work unchanged; waves doubled.
//  pass 1: per-block 32KB LDS bitmask via ds_or, dumped coalesced to
//          per-block region in d_ws (512 x 32KB = 16MB).
//  pass 2: 256 blocks x 256 thr; 8 segments x 32 lanes OR 64 regions each,
//          LDS-reduce, blend 256 float4/block with enhanced_weight.

#define N_LANDMARKS 8388608
#define N_BINS      262144            // 512*512
#define GRID_COLS   512
#define NWORDS      (N_BINS / 32)     // 8192 dwords = 32 KB bitmask
#define P1_BLOCKS   512
#define P1_THREADS  1024

// --- pass 1: bin into per-block LDS bitmask, dump coalesced ------------------

__global__ __launch_bounds__(P1_THREADS)
void bin_lds_kernel(const float4* __restrict__ lm2,
                    unsigned int* __restrict__ regions) {
    __shared__ unsigned int mask[NWORDS];
    const int tid = threadIdx.x;

    #pragma unroll
    for (int w = tid; w < NWORDS; w += P1_THREADS) mask[w] = 0u;
    __syncthreads();

    const int total = P1_BLOCKS * P1_THREADS;          // 524288 threads
    const int n4 = N_LANDMARKS / 2;                    // 4194304 float4s -> 8 iters
    int i = blockIdx.x * P1_THREADS + tid;
    #pragma unroll 8
    for (; i < n4; i += total) {
        float4 v = lm2[i];                             // (x0,y0,x1,y1)
        int c0 = min((int)(v.x * 0.0625f), GRID_COLS - 1);
        int r0 = min((int)(v.y * 0.0625f), GRID_COLS - 1);
        int c1 = min((int)(v.z * 0.0625f), GRID_COLS - 1);
        int r1 = min((int)(v.w * 0.0625f), GRID_COLS - 1);
        unsigned int i0 = (unsigned int)(r0 * GRID_COLS + c0);
        unsigned int i1 = (unsigned int)(r1 * GRID_COLS + c1);
        atomicOr(&mask[i0 >> 5], 1u << (i0 & 31));     // ds_or_b32, no return
        atomicOr(&mask[i1 >> 5], 1u << (i1 & 31));
    }
    __syncthreads();

    unsigned int* dst = regions + (size_t)blockIdx.x * NWORDS;
    #pragma unroll
    for (int w = tid; w < NWORDS; w += P1_THREADS) dst[w] = mask[w];
}

// --- pass 2: OR the 512 regions (8-way split), blend with enhanced_weight ----
// 256 blocks x 256 threads. Block owns 32 bitmask words = 1024 bins = 256 float4.

__global__ __launch_bounds__(256)
void merge_blend_kernel(const unsigned int* __restrict__ regions,
                        const float4* __restrict__ ew4,
                        float4* __restrict__ out4) {
    __shared__ unsigned int part[8][33];               // +1 pad: conflict-free reduce
    __shared__ unsigned int merged[32];

    const int t   = threadIdx.x;
    const int wl  = t & 31;                            // word within block
    const int seg = t >> 5;                            // region segment, 0..7
    const int w   = blockIdx.x * 32 + wl;              // global word index

    // OR 64 regions for this word; lanes wl=0..31 read 128B contiguous per region.
    const unsigned int* p = regions + (size_t)seg * 64 * NWORDS + w;
    unsigned int m = 0u;
    #pragma unroll
    for (int b = 0; b < 64; ++b)
        m |= p[(size_t)b * NWORDS];
    part[seg][wl] = m;
    __syncthreads();

    if (t < 32) {
        unsigned int mm = part[0][t];
        #pragma unroll
        for (int s = 1; s < 8; ++s) mm |= part[s][t];
        merged[t] = mm;
    }
    __syncthreads();

    // blend: thread t -> float4 t of this block (bins 4t..4t+3 local)
    const int g4 = blockIdx.x * 256 + t;
    const unsigned int mw = merged[t >> 3];
    const int sh = (t & 7) * 4;
    float4 e = ew4[g4];
    float4 r;
    r.x = ((mw >> (sh + 0)) & 1u) ? e.x : 1.0f;
    r.y = ((mw >> (sh + 1)) & 1u) ? e.y : 1.0f;
    r.z = ((mw >> (sh + 2)) & 1u) ? e.z : 1.0f;
    r.w = ((mw >> (sh + 3)) & 1u) ? e.w : 1.0f;
    out4[g4] = r;
}

// --- fallback (small ws): byte-flag path --------------------------------------

__global__ void scatter_flags_kernel(const float4* __restrict__ lm2,
                                     unsigned char* __restrict__ flags, int n4) {
    int i = blockIdx.x * blockDim.x + threadIdx.x;
    const int stride = gridDim.x * blockDim.x;
    for (; i < n4; i += stride) {
        float4 v = lm2[i];
        int c0 = min((int)(v.x * 0.0625f), GRID_COLS - 1);
        int r0 = min((int)(v.y * 0.0625f), GRID_COLS - 1);
        int c1 = min((int)(v.z * 0.0625f), GRID_COLS - 1);
        int r1 = min((int)(v.w * 0.0625f), GRID_COLS - 1);
        flags[r0 * GRID_COLS + c0] = (unsigned char)1;
        flags[r1 * GRID_COLS + c1] = (unsigned char)1;
    }
}

__global__ void blend_kernel(const unsigned char* __restrict__ flags,
                             const float* __restrict__ ew,
                             float* __restrict__ out) {
    int i = blockIdx.x * blockDim.x + threadIdx.x;
    out[i] = flags[i] ? ew[i] : 1.0f;
}

extern "C" void kernel_launch(void* const* d_in, const int* in_sizes, int n_in,
                              void* d_out, int out_size, void* d_ws, size_t ws_size,
                              hipStream_t stream) {
    const float4* lm2 = (const float4*)d_in[0];
    const float*  ew  = (const float*)d_in[1];
    float* out        = (float*)d_out;

    const size_t regions_bytes = (size_t)P1_BLOCKS * NWORDS * sizeof(unsigned int); // 16 MB

    if (ws_size >= regions_bytes) {
        unsigned int* regions = (unsigned int*)d_ws;
        bin_lds_kernel<<<P1_BLOCKS, P1_THREADS, 0, stream>>>(lm2, regions);
        merge_blend_kernel<<<NWORDS / 32, 256, 0, stream>>>(
            regions, (const float4*)ew, (float4*)out);
    } else {
        unsigned char* flags = (unsigned char*)d_ws;
        hipMemsetAsync(flags, 0, N_BINS, stream);
        scatter_flags_kernel<<<2048, 256, 0, stream>>>(lm2, flags, N_LANDMARKS / 2);
        blend_kernel<<<N_BINS / 256, 256, 0, stream>>>(flags, ew, out);
    }
}

// Round 5
// 20.071 us; speedup vs baseline: 1.1611x; 1.1611x over previous
//
#include <hip/hip_runtime.h>

// RegionAttention: bin 8M landmarks into a 512x512 grid; out[i] = enhanced[i]
// if any landmark falls in bin i else 1.0f.
//
// Round 5: revert to 256 blocks (round-4's 512-block/100%-occupancy experiment
// showed bin's core time is NOT wave-count-limited; the +3us was pure added
// dump/merge traffic). Attack per-wave MLP instead: the per-thread loop is
// exactly 16 iterations -> fully unroll with all 16 float4 loads issued first
// (statically-indexed reg array, 64 VGPRs, 4 waves/SIMD so budget is 512/wave).
// 4 KB in flight per CU vs round-3's 2 KB; ds_or for load k overlaps loads
// k+1..15 via compiler vmcnt(N) waits. Zero added memory traffic.
//  pass 1: per-block 32KB LDS bitmask via ds_or (fire-and-forget, no return),
//          dumped coalesced to per-block region in d_ws (256 x 32KB = 8MB).
//  pass 2: 256 blocks x 256 thr; 8 segments x 32 lanes OR 32 regions each,
//          LDS-reduce, blend 256 float4/block with enhanced_weight.

#define N_LANDMARKS 8388608
#define N_BINS      262144            // 512*512
#define GRID_COLS   512
#define NWORDS      (N_BINS / 32)     // 8192 dwords = 32 KB bitmask
#define P1_BLOCKS   256
#define P1_THREADS  1024
#define P1_ITERS    16                // n4 / (P1_BLOCKS*P1_THREADS) exactly

// --- pass 1: bin into per-block LDS bitmask, dump coalesced ------------------

__global__ __launch_bounds__(P1_THREADS)
void bin_lds_kernel(const float4* __restrict__ lm2,
                    unsigned int* __restrict__ regions) {
    __shared__ unsigned int mask[NWORDS];
    const int tid = threadIdx.x;

    #pragma unroll
    for (int w = tid; w < NWORDS; w += P1_THREADS) mask[w] = 0u;
    __syncthreads();

    const int total = P1_BLOCKS * P1_THREADS;          // 262144 threads
    const int base  = blockIdx.x * P1_THREADS + tid;

    // Issue all 16 independent loads first (static indices -> registers),
    // then consume; compiler interleaves ds_or with outstanding vmcnt.
    float4 buf[P1_ITERS];
    #pragma unroll
    for (int k = 0; k < P1_ITERS; ++k)
        buf[k] = lm2[base + k * total];

    #pragma unroll
    for (int k = 0; k < P1_ITERS; ++k) {
        float4 v = buf[k];                             // (x0,y0,x1,y1)
        int c0 = min((int)(v.x * 0.0625f), GRID_COLS - 1);
        int r0 = min((int)(v.y * 0.0625f), GRID_COLS - 1);
        int c1 = min((int)(v.z * 0.0625f), GRID_COLS - 1);
        int r1 = min((int)(v.w * 0.0625f), GRID_COLS - 1);
        unsigned int i0 = (unsigned int)(r0 * GRID_COLS + c0);
        unsigned int i1 = (unsigned int)(r1 * GRID_COLS + c1);
        atomicOr(&mask[i0 >> 5], 1u << (i0 & 31));     // ds_or_b32, no return
        atomicOr(&mask[i1 >> 5], 1u << (i1 & 31));
    }
    __syncthreads();

    unsigned int* dst = regions + (size_t)blockIdx.x * NWORDS;
    #pragma unroll
    for (int w = tid; w < NWORDS; w += P1_THREADS) dst[w] = mask[w];
}

// --- pass 2: OR the 256 regions (8-way split), blend with enhanced_weight ----
// 256 blocks x 256 threads. Block owns 32 bitmask words = 1024 bins = 256 float4.

__global__ __launch_bounds__(256)
void merge_blend_kernel(const unsigned int* __restrict__ regions,
                        const float4* __restrict__ ew4,
                        float4* __restrict__ out4) {
    __shared__ unsigned int part[8][33];               // +1 pad: conflict-free reduce
    __shared__ unsigned int merged[32];

    const int t   = threadIdx.x;
    const int wl  = t & 31;                            // word within block
    const int seg = t >> 5;                            // region segment, 0..7
    const int w   = blockIdx.x * 32 + wl;              // global word index

    // OR 32 regions for this word; lanes wl=0..31 read 128B contiguous per region.
    const unsigned int* p = regions + (size_t)seg * 32 * NWORDS + w;
    unsigned int m = 0u;
    #pragma unroll
    for (int b = 0; b < 32; ++b)
        m |= p[(size_t)b * NWORDS];
    part[seg][wl] = m;
    __syncthreads();

    if (t < 32) {
        unsigned int mm = part[0][t];
        #pragma unroll
        for (int s = 1; s < 8; ++s) mm |= part[s][t];
        merged[t] = mm;
    }
    __syncthreads();

    // blend: thread t -> float4 t of this block (bins 4t..4t+3 local)
    const int g4 = blockIdx.x * 256 + t;
    const unsigned int mw = merged[t >> 3];
    const int sh = (t & 7) * 4;
    float4 e = ew4[g4];
    float4 r;
    r.x = ((mw >> (sh + 0)) & 1u) ? e.x : 1.0f;
    r.y = ((mw >> (sh + 1)) & 1u) ? e.y : 1.0f;
    r.z = ((mw >> (sh + 2)) & 1u) ? e.z : 1.0f;
    r.w = ((mw >> (sh + 3)) & 1u) ? e.w : 1.0f;
    out4[g4] = r;
}

// --- fallback (small ws): byte-flag path --------------------------------------

__global__ void scatter_flags_kernel(const float4* __restrict__ lm2,
                                     unsigned char* __restrict__ flags, int n4) {
    int i = blockIdx.x * blockDim.x + threadIdx.x;
    const int stride = gridDim.x * blockDim.x;
    for (; i < n4; i += stride) {
        float4 v = lm2[i];
        int c0 = min((int)(v.x * 0.0625f), GRID_COLS - 1);
        int r0 = min((int)(v.y * 0.0625f), GRID_COLS - 1);
        int c1 = min((int)(v.z * 0.0625f), GRID_COLS - 1);
        int r1 = min((int)(v.w * 0.0625f), GRID_COLS - 1);
        flags[r0 * GRID_COLS + c0] = (unsigned char)1;
        flags[r1 * GRID_COLS + c1] = (unsigned char)1;
    }
}

__global__ void blend_kernel(const unsigned char* __restrict__ flags,
                             const float* __restrict__ ew,
                             float* __restrict__ out) {
    int i = blockIdx.x * blockDim.x + threadIdx.x;
    out[i] = flags[i] ? ew[i] : 1.0f;
}

extern "C" void kernel_launch(void* const* d_in, const int* in_sizes, int n_in,
                              void* d_out, int out_size, void* d_ws, size_t ws_size,
                              hipStream_t stream) {
    const float4* lm2 = (const float4*)d_in[0];
    const float*  ew  = (const float*)d_in[1];
    float* out        = (float*)d_out;

    const size_t regions_bytes = (size_t)P1_BLOCKS * NWORDS * sizeof(unsigned int); // 8 MB

    if (ws_size >= regions_bytes) {
        unsigned int* regions = (unsigned int*)d_ws;
        bin_lds_kernel<<<P1_BLOCKS, P1_THREADS, 0, stream>>>(lm2, regions);
        merge_blend_kernel<<<NWORDS / 32, 256, 0, stream>>>(
            regions, (const float4*)ew, (float4*)out);
    } else {
        unsigned char* flags = (unsigned char*)d_ws;
        hipMemsetAsync(flags, 0, N_BINS, stream);
        scatter_flags_kernel<<<2048, 256, 0, stream>>>(lm2, flags, N_LANDMARKS / 2);
        blend_kernel<<<N_BINS / 256, 256, 0, stream>>>(flags, ew, out);
    }
}